// Round 13
// baseline (118.401 us; speedup 1.0000x reference)
//
#include <hip/hip_runtime.h>

// DiffuseLR v11: 5 kernels + 1 memset.
//   fcT'[n][c] = dinv[n]*fc_w[c][n]
//   gT[s][c]   = dinv[s]*(sum_{e:src=s} w_e*fcT'[dst_e][c] + fcT'[s][c])
//   logits = x @ gT + b; out = softmax(logits)
// Fine-grain buckets (BN=32, 625 blocks) for the fused fold+gemm; deg built by
// fire-and-forget device atomics inside the scatter pass (no hist kernel).

#define N_NODES   20000
#define N_EDGES_C 640000
#define N_CLASSES 30
#define CPAD      32

// partition geometry
#define BN        32
#define NB        625                     // 20000/32 exactly
#define NSLAB     256
#define SLAB_E    (N_EDGES_C / NSLAB)     // 2500
#define ECAP      1440                    // mean 1024, sd ~32 -> 13 sigma margin

// fused fold+gemm geometry
#define XLD       129                     // xl[n][b] stride -> conflict-free
#define GTLD      33                      // gt[c][n] stride

// K1: scatter edges into fixed-capacity buckets + accumulate weighted in-degree.
// Per 2500-edge slab: LDS src cache + 625-bucket LDS histogram, one device
// atomicAdd per (block,bucket) range-reserve, then scatter records
// {(s_local<<15)|d, w_raw} and atomicAdd(&deg[d], w) (fire-and-forget).
__global__ __launch_bounds__(512) void k1_scatter(const int* __restrict__ src,
        const int* __restrict__ dst, const float* __restrict__ ew,
        float* __restrict__ deg, int* __restrict__ gcur,
        int2* __restrict__ erec) {
    __shared__ int ssrc[SLAB_E];      // 10 KB
    __shared__ int shist[NB];         // 2.5 KB
    __shared__ int scur[NB];          // 2.5 KB
    int slab = blockIdx.x;
    int t = threadIdx.x;
    int e0 = slab * SLAB_E;
    for (int i = t; i < NB; i += 512) shist[i] = 0;
    __syncthreads();
    const int4* s4 = (const int4*)(src + e0);
    for (int i = t; i < SLAB_E / 4; i += 512) {
        int4 sv = s4[i];
        ((int4*)ssrc)[i] = sv;
        atomicAdd(&shist[sv.x >> 5], 1);
        atomicAdd(&shist[sv.y >> 5], 1);
        atomicAdd(&shist[sv.z >> 5], 1);
        atomicAdd(&shist[sv.w >> 5], 1);
    }
    __syncthreads();
    for (int b = t; b < NB; b += 512)
        scur[b] = b * ECAP + atomicAdd(&gcur[b], shist[b]);   // range reserve
    __syncthreads();
    const int4* d4 = (const int4*)(dst + e0);
    const float4* w4 = (const float4*)(ew + e0);
    for (int i = t; i < SLAB_E / 4; i += 512) {
        int4 dv = d4[i]; float4 wv = w4[i];
        int4 sv = ((const int4*)ssrc)[i];
        int s, d, p;
        s = sv.x; d = dv.x;
        atomicAdd(&deg[d], wv.x);
        p = atomicAdd(&scur[s >> 5], 1);
        erec[p] = make_int2(((s & 31) << 15) | d, __float_as_int(wv.x));
        s = sv.y; d = dv.y;
        atomicAdd(&deg[d], wv.y);
        p = atomicAdd(&scur[s >> 5], 1);
        erec[p] = make_int2(((s & 31) << 15) | d, __float_as_int(wv.y));
        s = sv.z; d = dv.z;
        atomicAdd(&deg[d], wv.z);
        p = atomicAdd(&scur[s >> 5], 1);
        erec[p] = make_int2(((s & 31) << 15) | d, __float_as_int(wv.z));
        s = sv.w; d = dv.w;
        atomicAdd(&deg[d], wv.w);
        p = atomicAdd(&scur[s >> 5], 1);
        erec[p] = make_int2(((s & 31) << 15) | d, __float_as_int(wv.w));
    }
}

// K2: per 32-node group: dinv = rsqrt(deg+1) + fcT'[n][c] = dinv[n]*fc_w[c][n]
// (LDS-tiled transpose, all reads/writes coalesced).
__global__ __launch_bounds__(256) void k2_prep(const float* __restrict__ deg,
        const float* __restrict__ fc_w, float* __restrict__ dinv,
        float* __restrict__ fcT) {
    __shared__ float tile[CPAD][BN + 1];
    __shared__ float sdinv[BN];
    int n0 = blockIdx.x * BN;
    int t = threadIdx.x;
    if (t < BN) {
        float di = rsqrtf(deg[n0 + t] + 1.0f);   // +1 = self-loop weight
        dinv[n0 + t] = di;
        sdinv[t] = di;
    }
    #pragma unroll
    for (int k = 0; k < 4; k++) {        // load 32c x 32n, coalesced rows
        int idx = k * 256 + t;
        int c = idx >> 5, nn = idx & 31;
        tile[c][nn] = (c < N_CLASSES) ? fc_w[c * N_NODES + n0 + nn] : 0.f;
    }
    __syncthreads();
    #pragma unroll
    for (int k = 0; k < 4; k++) {        // write fcT' = dinv*tile, coalesced
        int idx = k * 256 + t;
        int nn = idx >> 5, c = idx & 31;
        fcT[(size_t)(n0 + nn) * CPAD + c] = sdinv[nn] * tile[c][nn];
    }
}

// K3: fused fold+GEMM per 32-node bucket. Phase 1: LDS counting sort by node +
// register gather into a gt LDS tile. Phase 2: stage x chunk, compute logits
// partials for all 128 batches.
__global__ __launch_bounds__(512) void k3_foldgemm(const int2* __restrict__ erec,
        const int* __restrict__ gcur, const float* __restrict__ dinv,
        const float* __restrict__ fcT, const float* __restrict__ x,
        float* __restrict__ part) {
    __shared__ union {
        struct { int2 srt[ECAP]; int hist[BN]; int rowst[BN]; int cur[BN]; } f; // 11904 B
        struct { float xl[BN * XLD]; float gt[CPAD * GTLD]; } g;                // 20736 B
    } sm;
    float* gt = sm.g.gt;   // offset 16512 > 11904: disjoint from f during fold
    int bucket = blockIdx.x;
    int t = threadIdx.x;
    int nlo = bucket * BN;
    int bstart = bucket * ECAP;
    int len = min(gcur[bucket], ECAP);

    // ---- counting sort by node ----
    if (t < BN) sm.f.hist[t] = 0;
    __syncthreads();
    for (int i = t; i < len; i += 512)
        atomicAdd(&sm.f.hist[((unsigned)erec[bstart + i].x) >> 15], 1);
    __syncthreads();
    if (t < BN) {
        int h = sm.f.hist[t];
        int v = h;
        #pragma unroll
        for (int o = 1; o < BN; o <<= 1) {
            int u = __shfl_up(v, o, BN);
            if (t >= o) v += u;
        }
        sm.f.rowst[t] = v - h;
        sm.f.cur[t]   = v - h;
    }
    __syncthreads();
    for (int i = t; i < len; i += 512) {
        int2 r = erec[bstart + i];
        int p = atomicAdd(&sm.f.cur[((unsigned)r.x) >> 15], 1);
        sm.f.srt[p] = r;
    }
    __syncthreads();

    // ---- register gather -> gt tile (disjoint from f region) ----
    int c = t & 31;
    int grp = t >> 5;                    // 0..15; nodes grp, grp+16
    #pragma unroll
    for (int half = 0; half < 2; half++) {
        int nn = grp + half * 16;
        int n = nlo + nn;
        float acc  = fcT[(size_t)n * CPAD + c];   // self-loop (pre-scaled)
        float acc2 = 0.f;
        int i = sm.f.rowst[nn], re = i + sm.f.hist[nn];
        for (; i + 1 < re; i += 2) {
            int2 r0 = sm.f.srt[i], r1 = sm.f.srt[i + 1];       // LDS broadcast
            acc  += __int_as_float(r0.y) * fcT[(size_t)(r0.x & 0x7FFF) * CPAD + c];
            acc2 += __int_as_float(r1.y) * fcT[(size_t)(r1.x & 0x7FFF) * CPAD + c];
        }
        if (i < re) {
            int2 r0 = sm.f.srt[i];
            acc += __int_as_float(r0.y) * fcT[(size_t)(r0.x & 0x7FFF) * CPAD + c];
        }
        gt[c * GTLD + nn] = dinv[n] * (acc + acc2);
    }
    __syncthreads();   // gt complete; f region dead

    // ---- gemm: stage x[128][32-chunk] transposed to xl[n][b] ----
    for (int o = t; o < 128 * BN; o += 512) {
        int b = o >> 5, n = o & 31;
        sm.g.xl[n * XLD + b] = x[(size_t)b * N_NODES + nlo + n];
    }
    __syncthreads();

    int wv = t >> 6, l = t & 63;   // wave = class group, lane = batch
    float a00 = 0.f, a01 = 0.f, a10 = 0.f, a11 = 0.f;
    float a20 = 0.f, a21 = 0.f, a30 = 0.f, a31 = 0.f;
    #pragma unroll 8
    for (int n = 0; n < BN; n++) {
        float x0 = sm.g.xl[n * XLD + l];
        float x1 = sm.g.xl[n * XLD + 64 + l];
        float g0 = gt[(wv)      * GTLD + n];   // wave-uniform broadcast
        float g1 = gt[(wv +  8) * GTLD + n];
        float g2 = gt[(wv + 16) * GTLD + n];
        float g3 = gt[(wv + 24) * GTLD + n];
        a00 += x0 * g0; a01 += x1 * g0;
        a10 += x0 * g1; a11 += x1 * g1;
        a20 += x0 * g2; a21 += x1 * g2;
        a30 += x0 * g3; a31 += x1 * g3;
    }
    float* pb = part + (size_t)bucket * CPAD * 128;
    pb[(wv)      * 128 + l]      = a00;
    pb[(wv)      * 128 + 64 + l] = a01;
    pb[(wv +  8) * 128 + l]      = a10;
    pb[(wv +  8) * 128 + 64 + l] = a11;
    pb[(wv + 16) * 128 + l]      = a20;
    pb[(wv + 16) * 128 + 64 + l] = a21;
    pb[(wv + 24) * 128 + l]      = a30;
    pb[(wv + 24) * 128 + 64 + l] = a31;
}

// K4: chunk reduction: lpart[q][c][b] = sum_{ch ≡ q mod 5} part[ch][c][b]
__global__ __launch_bounds__(128) void k4_lred(const float* __restrict__ part,
        float* __restrict__ lpart) {
    int c = blockIdx.x, q = blockIdx.y;
    int b = threadIdx.x;
    float s = 0.f;
    for (int ch = q; ch < NB; ch += 5)
        s += part[(size_t)ch * CPAD * 128 + c * 128 + b];
    lpart[(q * CPAD + c) * 128 + b] = s;
}

// K5: final sum + bias + softmax
__global__ void k5_smax(const float* __restrict__ lpart,
        const float* __restrict__ fc_b, float* __restrict__ out) {
    int b = threadIdx.x;
    float v[N_CLASSES], m = -1e30f;
    #pragma unroll
    for (int c = 0; c < N_CLASSES; c++) {
        float s = fc_b[c];
        #pragma unroll
        for (int q = 0; q < 5; q++) s += lpart[(q * CPAD + c) * 128 + b];
        v[c] = s; m = fmaxf(m, s);
    }
    float s = 0.f;
    #pragma unroll
    for (int c = 0; c < N_CLASSES; c++) { v[c] = __expf(v[c] - m); s += v[c]; }
    float inv = 1.0f / s;
    #pragma unroll
    for (int c = 0; c < N_CLASSES; c++) out[b * N_CLASSES + c] = v[c] * inv;
}

extern "C" void kernel_launch(void* const* d_in, const int* in_sizes, int n_in,
                              void* d_out, int out_size, void* d_ws, size_t ws_size,
                              hipStream_t stream) {
    const float* x          = (const float*)d_in[0];
    const int*   edge_index = (const int*)d_in[1];
    const float* ew         = (const float*)d_in[2];
    const float* fc_w       = (const float*)d_in[3];
    const float* fc_b       = (const float*)d_in[4];
    float* out = (float*)d_out;

    const int* src = edge_index;
    const int* dst = edge_index + N_EDGES_C;

    // ws layout (float slots):
    float* part  = (float*)d_ws;                             // 2,560,000
    int2*  erec  = (int2*)(part + (size_t)NB * CPAD * 128);  // 900,000 int2
    float* deg   = (float*)(erec + (size_t)NB * ECAP);       // 20,000
    int*   gcur  = (int*)(deg + N_NODES);                    // 625 (pad 640)
    float* dinv  = (float*)(gcur + 640);                     // 20,000
    float* fcT   = dinv + N_NODES;                           // 640,000
    float* lpart = fcT + (size_t)N_NODES * CPAD;             // 20,480

    // zero deg + gcur in one async memset (adjacent)
    hipMemsetAsync(deg, 0, (N_NODES + 640) * sizeof(float), stream);

    k1_scatter<<<NSLAB, 512, 0, stream>>>(src, dst, ew, deg, gcur, erec);
    k2_prep<<<NB, 256, 0, stream>>>(deg, fc_w, dinv, fcT);
    k3_foldgemm<<<NB, 512, 0, stream>>>(erec, gcur, dinv, fcT, x, part);
    k4_lred<<<dim3(N_CLASSES, 5), 128, 0, stream>>>(part, lpart);
    k5_smax<<<1, 128, 0, stream>>>(lpart, fc_b, out);
}

// Round 14
// 96.144 us; speedup vs baseline: 1.2315x; 1.2315x over previous
//
#include <hip/hip_runtime.h>

// DiffuseLR v12: 4 kernels + memset.
//   fcT'[n][c] = dinv[n]*fc_w[c][n]
//   gT[s][c]   = dinv[s]*(sum_{e:src=s} w_e*fcT'[dst_e][c] + fcT'[s][c])
//   logits = x @ gT + b; out = softmax(logits)
// K1 co-launches deg-hist blocks and scatter blocks (independent roles: scatter
// stores RAW w, so it never waits on dinv). BN=32 fused fold+gemm (proven R13).

#define N_NODES   20000
#define N_EDGES_C 640000
#define N_CLASSES 30
#define CPAD      32

// deg-hist geometry
#define HBLKS     32
#define HNODES    10000
#define HEDGES    (N_EDGES_C / HBLKS)     // 20000

// partition geometry
#define BN        32
#define NB        625                     // 20000/32 exactly
#define NSLAB     256
#define SLAB_E    (N_EDGES_C / NSLAB)     // 2500
#define ECAP      1440                    // mean 1024, sd ~32 -> 13 sigma margin

// fused fold+gemm geometry
#define XLD       129                     // xl[n][b] stride -> conflict-free
#define GTLD      33                      // gt[c][n] stride

// K1: blocks [0,64): weighted in-degree LDS histogram per (edge-slab, half);
//     blocks [64,320): scatter slab into fixed-capacity buckets (raw w).
__global__ __launch_bounds__(512) void k1_histscatter(const int* __restrict__ src,
        const int* __restrict__ dst, const float* __restrict__ ew,
        float* __restrict__ degp, int* __restrict__ gcur,
        int2* __restrict__ erec) {
    __shared__ union {
        float h[HNODES];                                               // 40 KB
        struct { int ssrc[SLAB_E]; int shist[NB]; int scur[NB]; } s;   // 15 KB
    } sm;
    int bid = blockIdx.x;
    int t = threadIdx.x;
    if (bid < 2 * HBLKS) {
        // ---- deg-hist role ----
        int eb = bid >> 1, half = bid & 1;
        int nbase = half * HNODES;
        for (int i = t; i < HNODES; i += 512) sm.h[i] = 0.f;
        __syncthreads();
        const int4* d4 = (const int4*)(dst + eb * HEDGES);
        const float4* w4 = (const float4*)(ew + eb * HEDGES);
        for (int i = t; i < HEDGES / 4; i += 512) {
            int4 dv = d4[i]; float4 wv = w4[i];
            unsigned r;
            r = (unsigned)(dv.x - nbase); if (r < HNODES) atomicAdd(&sm.h[r], wv.x);
            r = (unsigned)(dv.y - nbase); if (r < HNODES) atomicAdd(&sm.h[r], wv.y);
            r = (unsigned)(dv.z - nbase); if (r < HNODES) atomicAdd(&sm.h[r], wv.z);
            r = (unsigned)(dv.w - nbase); if (r < HNODES) atomicAdd(&sm.h[r], wv.w);
        }
        __syncthreads();
        float* outp = degp + (size_t)bid * HNODES;
        for (int i = t; i < HNODES; i += 512) outp[i] = sm.h[i];
    } else {
        // ---- scatter role ----
        int slab = bid - 2 * HBLKS;
        int e0 = slab * SLAB_E;
        for (int i = t; i < NB; i += 512) sm.s.shist[i] = 0;
        __syncthreads();
        const int4* s4 = (const int4*)(src + e0);
        for (int i = t; i < SLAB_E / 4; i += 512) {
            int4 sv = s4[i];
            ((int4*)sm.s.ssrc)[i] = sv;
            atomicAdd(&sm.s.shist[sv.x >> 5], 1);
            atomicAdd(&sm.s.shist[sv.y >> 5], 1);
            atomicAdd(&sm.s.shist[sv.z >> 5], 1);
            atomicAdd(&sm.s.shist[sv.w >> 5], 1);
        }
        __syncthreads();
        for (int b = t; b < NB; b += 512)
            sm.s.scur[b] = b * ECAP + atomicAdd(&gcur[b], sm.s.shist[b]);
        __syncthreads();
        const int4* d4 = (const int4*)(dst + e0);
        const float4* w4 = (const float4*)(ew + e0);
        for (int i = t; i < SLAB_E / 4; i += 512) {
            int4 dv = d4[i]; float4 wv = w4[i];
            int4 sv = ((const int4*)sm.s.ssrc)[i];
            int s, p;
            s = sv.x; p = atomicAdd(&sm.s.scur[s >> 5], 1);
            erec[p] = make_int2(((s & 31) << 15) | dv.x, __float_as_int(wv.x));
            s = sv.y; p = atomicAdd(&sm.s.scur[s >> 5], 1);
            erec[p] = make_int2(((s & 31) << 15) | dv.y, __float_as_int(wv.y));
            s = sv.z; p = atomicAdd(&sm.s.scur[s >> 5], 1);
            erec[p] = make_int2(((s & 31) << 15) | dv.z, __float_as_int(wv.z));
            s = sv.w; p = atomicAdd(&sm.s.scur[s >> 5], 1);
            erec[p] = make_int2(((s & 31) << 15) | dv.w, __float_as_int(wv.w));
        }
    }
}

// K2: per 32-node bucket: dinv from the 64 slab-partials (threads 0..31,
// coalesced 128B line per slab) + fcT'[n][c] = dinv[n]*fc_w[c][n] transpose.
__global__ __launch_bounds__(256) void k2_prep(const float* __restrict__ degp,
        const float* __restrict__ fc_w, float* __restrict__ dinv,
        float* __restrict__ fcT) {
    __shared__ float tile[CPAD][BN + 1];
    __shared__ float sdinv[BN];
    int n0 = blockIdx.x * BN;
    int t = threadIdx.x;
    if (t < BN) {
        int n = n0 + t;
        int half = n / HNODES, nn = n - half * HNODES;
        float s = 1.0f;   // self-loop weight
        for (int eb = 0; eb < HBLKS; eb++)
            s += degp[(size_t)((eb << 1) | half) * HNODES + nn];
        float di = rsqrtf(s);
        dinv[n] = di;
        sdinv[t] = di;
    }
    #pragma unroll
    for (int k = 0; k < 4; k++) {        // load 32c x 32n, coalesced rows
        int idx = k * 256 + t;
        int c = idx >> 5, nn = idx & 31;
        tile[c][nn] = (c < N_CLASSES) ? fc_w[c * N_NODES + n0 + nn] : 0.f;
    }
    __syncthreads();
    #pragma unroll
    for (int k = 0; k < 4; k++) {        // write fcT' = dinv*tile, coalesced
        int idx = k * 256 + t;
        int nn = idx >> 5, c = idx & 31;
        fcT[(size_t)(n0 + nn) * CPAD + c] = sdinv[nn] * tile[c][nn];
    }
}

// K3: fused fold+GEMM per 32-node bucket (unchanged from R13 — proven).
__global__ __launch_bounds__(512) void k3_foldgemm(const int2* __restrict__ erec,
        const int* __restrict__ gcur, const float* __restrict__ dinv,
        const float* __restrict__ fcT, const float* __restrict__ x,
        float* __restrict__ part) {
    __shared__ union {
        struct { int2 srt[ECAP]; int hist[BN]; int rowst[BN]; int cur[BN]; } f; // 11904 B
        struct { float xl[BN * XLD]; float gt[CPAD * GTLD]; } g;                // 20736 B
    } sm;
    float* gt = sm.g.gt;   // offset 16512 > 11904: disjoint from f during fold
    int bucket = blockIdx.x;
    int t = threadIdx.x;
    int nlo = bucket * BN;
    int bstart = bucket * ECAP;
    int len = min(gcur[bucket], ECAP);

    if (t < BN) sm.f.hist[t] = 0;
    __syncthreads();
    for (int i = t; i < len; i += 512)
        atomicAdd(&sm.f.hist[((unsigned)erec[bstart + i].x) >> 15], 1);
    __syncthreads();
    if (t < BN) {
        int h = sm.f.hist[t];
        int v = h;
        #pragma unroll
        for (int o = 1; o < BN; o <<= 1) {
            int u = __shfl_up(v, o, BN);
            if (t >= o) v += u;
        }
        sm.f.rowst[t] = v - h;
        sm.f.cur[t]   = v - h;
    }
    __syncthreads();
    for (int i = t; i < len; i += 512) {
        int2 r = erec[bstart + i];
        int p = atomicAdd(&sm.f.cur[((unsigned)r.x) >> 15], 1);
        sm.f.srt[p] = r;
    }
    __syncthreads();

    int c = t & 31;
    int grp = t >> 5;                    // 0..15; nodes grp, grp+16
    #pragma unroll
    for (int half = 0; half < 2; half++) {
        int nn = grp + half * 16;
        int n = nlo + nn;
        float acc  = fcT[(size_t)n * CPAD + c];   // self-loop (pre-scaled)
        float acc2 = 0.f;
        int i = sm.f.rowst[nn], re = i + sm.f.hist[nn];
        for (; i + 1 < re; i += 2) {
            int2 r0 = sm.f.srt[i], r1 = sm.f.srt[i + 1];       // LDS broadcast
            acc  += __int_as_float(r0.y) * fcT[(size_t)(r0.x & 0x7FFF) * CPAD + c];
            acc2 += __int_as_float(r1.y) * fcT[(size_t)(r1.x & 0x7FFF) * CPAD + c];
        }
        if (i < re) {
            int2 r0 = sm.f.srt[i];
            acc += __int_as_float(r0.y) * fcT[(size_t)(r0.x & 0x7FFF) * CPAD + c];
        }
        gt[c * GTLD + nn] = dinv[n] * (acc + acc2);
    }
    __syncthreads();   // gt complete; f region dead

    for (int o = t; o < 128 * BN; o += 512) {
        int b = o >> 5, n = o & 31;
        sm.g.xl[n * XLD + b] = x[(size_t)b * N_NODES + nlo + n];
    }
    __syncthreads();

    int wv = t >> 6, l = t & 63;   // wave = class group, lane = batch
    float a00 = 0.f, a01 = 0.f, a10 = 0.f, a11 = 0.f;
    float a20 = 0.f, a21 = 0.f, a30 = 0.f, a31 = 0.f;
    #pragma unroll 8
    for (int n = 0; n < BN; n++) {
        float x0 = sm.g.xl[n * XLD + l];
        float x1 = sm.g.xl[n * XLD + 64 + l];
        float g0 = gt[(wv)      * GTLD + n];   // wave-uniform broadcast
        float g1 = gt[(wv +  8) * GTLD + n];
        float g2 = gt[(wv + 16) * GTLD + n];
        float g3 = gt[(wv + 24) * GTLD + n];
        a00 += x0 * g0; a01 += x1 * g0;
        a10 += x0 * g1; a11 += x1 * g1;
        a20 += x0 * g2; a21 += x1 * g2;
        a30 += x0 * g3; a31 += x1 * g3;
    }
    float* pb = part + (size_t)bucket * CPAD * 128;
    pb[(wv)      * 128 + l]      = a00;
    pb[(wv)      * 128 + 64 + l] = a01;
    pb[(wv +  8) * 128 + l]      = a10;
    pb[(wv +  8) * 128 + 64 + l] = a11;
    pb[(wv + 16) * 128 + l]      = a20;
    pb[(wv + 16) * 128 + 64 + l] = a21;
    pb[(wv + 24) * 128 + l]      = a30;
    pb[(wv + 24) * 128 + 64 + l] = a31;
}

// K4: chunk reduction: lpart[q][c][b] = sum_{ch ≡ q mod 5} part[ch][c][b]
__global__ __launch_bounds__(128) void k4_lred(const float* __restrict__ part,
        float* __restrict__ lpart) {
    int c = blockIdx.x, q = blockIdx.y;
    int b = threadIdx.x;
    float s = 0.f;
    for (int ch = q; ch < NB; ch += 5)
        s += part[(size_t)ch * CPAD * 128 + c * 128 + b];
    lpart[(q * CPAD + c) * 128 + b] = s;
}

// K5: final sum + bias + softmax
__global__ void k5_smax(const float* __restrict__ lpart,
        const float* __restrict__ fc_b, float* __restrict__ out) {
    int b = threadIdx.x;
    float v[N_CLASSES], m = -1e30f;
    #pragma unroll
    for (int c = 0; c < N_CLASSES; c++) {
        float s = fc_b[c];
        #pragma unroll
        for (int q = 0; q < 5; q++) s += lpart[(q * CPAD + c) * 128 + b];
        v[c] = s; m = fmaxf(m, s);
    }
    float s = 0.f;
    #pragma unroll
    for (int c = 0; c < N_CLASSES; c++) { v[c] = __expf(v[c] - m); s += v[c]; }
    float inv = 1.0f / s;
    #pragma unroll
    for (int c = 0; c < N_CLASSES; c++) out[b * N_CLASSES + c] = v[c] * inv;
}

extern "C" void kernel_launch(void* const* d_in, const int* in_sizes, int n_in,
                              void* d_out, int out_size, void* d_ws, size_t ws_size,
                              hipStream_t stream) {
    const float* x          = (const float*)d_in[0];
    const int*   edge_index = (const int*)d_in[1];
    const float* ew         = (const float*)d_in[2];
    const float* fc_w       = (const float*)d_in[3];
    const float* fc_b       = (const float*)d_in[4];
    float* out = (float*)d_out;

    const int* src = edge_index;
    const int* dst = edge_index + N_EDGES_C;

    // ws layout (float slots), time-disjoint aliasing:
    //   A (2,560,000): degp [K1..K2] (640,000) -> part [K3..K4]
    float* A     = (float*)d_ws;                             // 2,560,000
    int2*  erec  = (int2*)(A + (size_t)NB * CPAD * 128);     // 900,000 int2
    float* dinv  = (float*)(erec + (size_t)NB * ECAP);       // 20,000
    int*   gcur  = (int*)(dinv + N_NODES);                   // 625 (pad 640)
    float* fcT   = (float*)(gcur + 640);                     // 640,000
    float* lpart = fcT + (size_t)N_NODES * CPAD;             // 20,480

    float* degp = A;
    float* part = A;

    hipMemsetAsync(gcur, 0, 640 * sizeof(int), stream);

    k1_histscatter<<<2 * HBLKS + NSLAB, 512, 0, stream>>>(src, dst, ew, degp,
                                                          gcur, erec);
    k2_prep<<<NB, 256, 0, stream>>>(degp, fc_w, dinv, fcT);
    k3_foldgemm<<<NB, 512, 0, stream>>>(erec, gcur, dinv, fcT, x, part);
    k4_lred<<<dim3(N_CLASSES, 5), 128, 0, stream>>>(part, lpart);
    k5_smax<<<1, 128, 0, stream>>>(lpart, fc_b, out);
}